// Round 1
// baseline (217.866 us; speedup 1.0000x reference)
//
#include <hip/hip_runtime.h>

// Elementwise fused diag-Hessian-preconditioned Adam update.
// N = 33,554,432 f32 elements; memory-bound (32 B/elem, ~1.07 GB traffic).

__device__ __forceinline__ void update_one(float var, float g, float h, float m,
                                           float v, float inv_bc1, float inv_bc2,
                                           float& out_var, float& out_m, float& out_v) {
    const float COEF_H      = 0.0405f;   // 5 * 0.3^4
    const float COEF_OUTERDP = 0.54f;    // 5*4 * 0.3^3
    float g2   = g * g;
    float newH = fabsf(COEF_OUTERDP * g2 + COEF_H * h) + 0.01f;
    float d2W  = g * COEF_H / newH;
    float m_new = 0.9f * m + 0.1f * d2W;
    float m_hat = m_new * inv_bc1;
    float v_new = 0.999f * v + 0.001f * g2;
    float v_hat = v_new * inv_bc2;
    out_var = var - 7.5e-05f * m_hat / (sqrtf(v_hat) + 1e-07f);
    out_m   = m_new;
    out_v   = v_new;
}

__global__ __launch_bounds__(256) void fused_adam_kernel(
    const float4* __restrict__ var,
    const float4* __restrict__ g,
    const float4* __restrict__ h,
    const float4* __restrict__ m,
    const float4* __restrict__ v,
    const int* __restrict__ step_ptr,
    float4* __restrict__ out_var,
    float4* __restrict__ out_m,
    float4* __restrict__ out_v,
    int n4)
{
    // Bias corrections computed once per thread (step read from device scalar).
    float sf = (float)(*step_ptr);
    float inv_bc1 = 1.0f / (1.0f - powf(0.9f, sf));
    float inv_bc2 = 1.0f / (1.0f - powf(0.999f, sf));

    int stride = gridDim.x * blockDim.x;
    for (int i = blockIdx.x * blockDim.x + threadIdx.x; i < n4; i += stride) {
        float4 wv = var[i];
        float4 gv = g[i];
        float4 hv = h[i];
        float4 mv = m[i];
        float4 vv = v[i];
        float4 ow, om, ov;
        update_one(wv.x, gv.x, hv.x, mv.x, vv.x, inv_bc1, inv_bc2, ow.x, om.x, ov.x);
        update_one(wv.y, gv.y, hv.y, mv.y, vv.y, inv_bc1, inv_bc2, ow.y, om.y, ov.y);
        update_one(wv.z, gv.z, hv.z, mv.z, vv.z, inv_bc1, inv_bc2, ow.z, om.z, ov.z);
        update_one(wv.w, gv.w, hv.w, mv.w, vv.w, inv_bc1, inv_bc2, ow.w, om.w, ov.w);
        out_var[i] = ow;
        out_m[i]   = om;
        out_v[i]   = ov;
    }
}

extern "C" void kernel_launch(void* const* d_in, const int* in_sizes, int n_in,
                              void* d_out, int out_size, void* d_ws, size_t ws_size,
                              hipStream_t stream) {
    const int N = in_sizes[0];           // 33,554,432
    const int n4 = N / 4;                // N is 2^25, divisible by 4

    const float4* var = (const float4*)d_in[0];
    const float4* g   = (const float4*)d_in[1];
    const float4* h   = (const float4*)d_in[2];
    const float4* m   = (const float4*)d_in[3];
    const float4* v   = (const float4*)d_in[4];
    const int* step   = (const int*)d_in[5];

    float* out = (float*)d_out;
    float4* out_var = (float4*)(out);
    float4* out_m   = (float4*)(out + (size_t)N);
    float4* out_v   = (float4*)(out + 2 * (size_t)N);

    const int block = 256;
    int grid = 2048;                     // 256 CU x 8 blocks; grid-stride covers the rest
    int needed = (n4 + block - 1) / block;
    if (needed < grid) grid = needed;

    fused_adam_kernel<<<grid, block, 0, stream>>>(var, g, h, m, v, step,
                                                  out_var, out_m, out_v, n4);
}

// Round 3
// 197.190 us; speedup vs baseline: 1.1049x; 1.1049x over previous
//
#include <hip/hip_runtime.h>

// Elementwise fused diag-Hessian-preconditioned Adam update.
// N = 33,554,432 f32; memory-bound. Round 3: 4x unroll MLP + NT stores
// (NT via native clang vector type; HIP_vector_type rejected by the builtin).

#define UNROLL 4

typedef float fx4 __attribute__((ext_vector_type(4)));

__device__ __forceinline__ void update_one(float var, float g, float h, float m,
                                           float v, float inv_bc1, float inv_bc2,
                                           float& out_var, float& out_m, float& out_v) {
    const float COEF_H       = 0.0405f;  // 5 * 0.3^4
    const float COEF_OUTERDP = 0.54f;    // 5*4 * 0.3^3
    float g2   = g * g;
    float newH = fabsf(COEF_OUTERDP * g2 + COEF_H * h) + 0.01f;
    float d2W  = g * COEF_H / newH;
    float m_new = 0.9f * m + 0.1f * d2W;
    float m_hat = m_new * inv_bc1;
    float v_new = 0.999f * v + 0.001f * g2;
    float v_hat = v_new * inv_bc2;
    out_var = var - 7.5e-05f * m_hat / (sqrtf(v_hat) + 1e-07f);
    out_m   = m_new;
    out_v   = v_new;
}

__global__ __launch_bounds__(256, 4) void fused_adam_kernel(
    const fx4* __restrict__ var,
    const fx4* __restrict__ g,
    const fx4* __restrict__ h,
    const fx4* __restrict__ m,
    const fx4* __restrict__ v,
    const int* __restrict__ step_ptr,
    fx4* __restrict__ out_var,
    fx4* __restrict__ out_m,
    fx4* __restrict__ out_v)
{
    float sf = (float)(*step_ptr);
    float inv_bc1 = 1.0f / (1.0f - powf(0.9f, sf));
    float inv_bc2 = 1.0f / (1.0f - powf(0.999f, sf));

    // Flat decomposition: each block owns 256*UNROLL consecutive float4s.
    int base = blockIdx.x * (256 * UNROLL) + threadIdx.x;

    fx4 wv[UNROLL], gv[UNROLL], hv[UNROLL], mv[UNROLL], vv[UNROLL];

    // Issue all 20 loads (5 streams x 4 offsets) before any wait.
#pragma unroll
    for (int u = 0; u < UNROLL; ++u) wv[u] = var[base + u * 256];
#pragma unroll
    for (int u = 0; u < UNROLL; ++u) gv[u] = g[base + u * 256];
#pragma unroll
    for (int u = 0; u < UNROLL; ++u) hv[u] = h[base + u * 256];
#pragma unroll
    for (int u = 0; u < UNROLL; ++u) mv[u] = m[base + u * 256];
#pragma unroll
    for (int u = 0; u < UNROLL; ++u) vv[u] = v[base + u * 256];

    fx4 ow[UNROLL], om[UNROLL], ov[UNROLL];
#pragma unroll
    for (int u = 0; u < UNROLL; ++u) {
#pragma unroll
        for (int j = 0; j < 4; ++j) {
            float a, b, c;
            update_one(wv[u][j], gv[u][j], hv[u][j], mv[u][j], vv[u][j],
                       inv_bc1, inv_bc2, a, b, c);
            ow[u][j] = a; om[u][j] = b; ov[u][j] = c;
        }
    }

    // Non-temporal stores: outputs are write-once, keep L3 for the inputs.
#pragma unroll
    for (int u = 0; u < UNROLL; ++u)
        __builtin_nontemporal_store(ow[u], &out_var[base + u * 256]);
#pragma unroll
    for (int u = 0; u < UNROLL; ++u)
        __builtin_nontemporal_store(om[u], &out_m[base + u * 256]);
#pragma unroll
    for (int u = 0; u < UNROLL; ++u)
        __builtin_nontemporal_store(ov[u], &out_v[base + u * 256]);
}

extern "C" void kernel_launch(void* const* d_in, const int* in_sizes, int n_in,
                              void* d_out, int out_size, void* d_ws, size_t ws_size,
                              hipStream_t stream) {
    const int N = in_sizes[0];           // 33,554,432 = 2^25
    const int n4 = N / 4;                // 2^23 float4s

    const fx4* var = (const fx4*)d_in[0];
    const fx4* g   = (const fx4*)d_in[1];
    const fx4* h   = (const fx4*)d_in[2];
    const fx4* m   = (const fx4*)d_in[3];
    const fx4* v   = (const fx4*)d_in[4];
    const int* step = (const int*)d_in[5];

    float* out = (float*)d_out;
    fx4* out_var = (fx4*)(out);
    fx4* out_m   = (fx4*)(out + (size_t)N);
    fx4* out_v   = (fx4*)(out + 2 * (size_t)N);

    // n4 = 8,388,608; per block = 256*UNROLL = 1024 float4 -> exactly 8192 blocks.
    const int block = 256;
    const int grid = n4 / (block * UNROLL);

    fused_adam_kernel<<<grid, block, 0, stream>>>(var, g, h, m, v, step,
                                                  out_var, out_m, out_v);
}

// Round 4
// 194.976 us; speedup vs baseline: 1.1174x; 1.0114x over previous
//
#include <hip/hip_runtime.h>

// Elementwise fused diag-Hessian-preconditioned Adam update.
// N = 33,554,432 f32; memory-bound. Round 4: pin all 20 loads in flight with
// sched_barrier(0) — round-3 VGPR=36 proved the compiler was sinking loads
// into per-u groups, serializing the memory pipeline at ~3 TB/s.

#define UNROLL 4

typedef float fx4 __attribute__((ext_vector_type(4)));

__device__ __forceinline__ void update_one(float var, float g, float h, float m,
                                           float v, float inv_bc1, float inv_bc2,
                                           float& out_var, float& out_m, float& out_v) {
    const float COEF_H       = 0.0405f;  // 5 * 0.3^4
    const float COEF_OUTERDP = 0.54f;    // 5*4 * 0.3^3
    float g2   = g * g;
    float newH = fabsf(COEF_OUTERDP * g2 + COEF_H * h) + 0.01f;
    float d2W  = g * COEF_H / newH;
    float m_new = 0.9f * m + 0.1f * d2W;
    float m_hat = m_new * inv_bc1;
    float v_new = 0.999f * v + 0.001f * g2;
    float v_hat = v_new * inv_bc2;
    out_var = var - 7.5e-05f * m_hat / (sqrtf(v_hat) + 1e-07f);
    out_m   = m_new;
    out_v   = v_new;
}

__global__ __launch_bounds__(256, 4) void fused_adam_kernel(
    const fx4* __restrict__ var,
    const fx4* __restrict__ g,
    const fx4* __restrict__ h,
    const fx4* __restrict__ m,
    const fx4* __restrict__ v,
    const int* __restrict__ step_ptr,
    fx4* __restrict__ out_var,
    fx4* __restrict__ out_m,
    fx4* __restrict__ out_v)
{
    int base = blockIdx.x * (256 * UNROLL) + threadIdx.x;

    fx4 wv[UNROLL], gv[UNROLL], hv[UNROLL], mv[UNROLL], vv[UNROLL];

    // Issue ALL 20 loads, u-major (consumption order == issue order so the
    // compiler can emit cascaded counted vmcnt waits: 15, 10, 5, 0).
#pragma unroll
    for (int u = 0; u < UNROLL; ++u) {
        int i = base + u * 256;
        wv[u] = var[i];
        gv[u] = g[i];
        hv[u] = h[i];
        mv[u] = m[i];
        vv[u] = v[i];
    }
    // Forbid the scheduler from sinking loads below this point (it did so in
    // round 3 to save registers, serializing the memory pipeline).
    __builtin_amdgcn_sched_barrier(0);

    // Bias correction AFTER the loads are issued: its s_load + powf latency
    // hides under the outstanding vector loads.
    float sf = (float)(*step_ptr);
    float inv_bc1 = 1.0f / (1.0f - powf(0.9f, sf));
    float inv_bc2 = 1.0f / (1.0f - powf(0.999f, sf));

#pragma unroll
    for (int u = 0; u < UNROLL; ++u) {
        fx4 ow, om, ov;
#pragma unroll
        for (int j = 0; j < 4; ++j) {
            float a, b, c;
            update_one(wv[u][j], gv[u][j], hv[u][j], mv[u][j], vv[u][j],
                       inv_bc1, inv_bc2, a, b, c);
            ow[j] = a; om[j] = b; ov[j] = c;
        }
        int i = base + u * 256;
        // Non-temporal: outputs are write-once, keep L3 for the inputs.
        __builtin_nontemporal_store(ow, &out_var[i]);
        __builtin_nontemporal_store(om, &out_m[i]);
        __builtin_nontemporal_store(ov, &out_v[i]);
    }
}

extern "C" void kernel_launch(void* const* d_in, const int* in_sizes, int n_in,
                              void* d_out, int out_size, void* d_ws, size_t ws_size,
                              hipStream_t stream) {
    const int N = in_sizes[0];           // 33,554,432 = 2^25
    const int n4 = N / 4;                // 2^23 float4s

    const fx4* var = (const fx4*)d_in[0];
    const fx4* g   = (const fx4*)d_in[1];
    const fx4* h   = (const fx4*)d_in[2];
    const fx4* m   = (const fx4*)d_in[3];
    const fx4* v   = (const fx4*)d_in[4];
    const int* step = (const int*)d_in[5];

    float* out = (float*)d_out;
    fx4* out_var = (fx4*)(out);
    fx4* out_m   = (fx4*)(out + (size_t)N);
    fx4* out_v   = (fx4*)(out + 2 * (size_t)N);

    // n4 = 8,388,608; per block = 256*UNROLL = 1024 float4 -> exactly 8192 blocks.
    const int block = 256;
    const int grid = n4 / (block * UNROLL);

    fused_adam_kernel<<<grid, block, 0, stream>>>(var, g, h, m, v, step,
                                                  out_var, out_m, out_v);
}